// Round 7
// baseline (106.397 us; speedup 1.0000x reference)
//
#include <hip/hip_runtime.h>
#include <hip/hip_bf16.h>
#include <math.h>

#define BATCH 4
#define CH    256
#define NPOS  4096
#define DQK   32
#define SHIFT 20.0f

typedef __attribute__((ext_vector_type(8))) short bf16x8;
typedef __attribute__((ext_vector_type(4))) float f32x4;

static __device__ __forceinline__ unsigned int pack_bf2(float a, float b) {
    __hip_bfloat162 h = __float22bfloat162_rn(make_float2(a, b));
    return *reinterpret_cast<unsigned int*>(&h);
}
static __device__ __forceinline__ unsigned short f2bf1(float f) {
    unsigned int u = __float_as_uint(f);
    u += 0x7fff + ((u >> 16) & 1);
    return (unsigned short)(u >> 16);
}
static __device__ __forceinline__ bf16x8 pack8(const float* v) {
    bf16x8 r;
    #pragma unroll
    for (int j = 0; j < 8; ++j) r[j] = (short)f2bf1(v[j]);
    return r;
}

// ---------------- Kernel 1: MFMA projection GEMM (unchanged from R6) ----------------
__global__ __launch_bounds__(256) void qkv_proj_mfma(
    const float* __restrict__ x,
    const float* __restrict__ Wq, const float* __restrict__ bq,
    const float* __restrict__ Wk, const float* __restrict__ bk,
    const float* __restrict__ Wv, const float* __restrict__ bv,
    __hip_bfloat16* __restrict__ qb, __hip_bfloat16* __restrict__ kb,
    __hip_bfloat16* __restrict__ vb)
{
    const int tid  = threadIdx.x;
    const int wave = tid >> 6, lane = tid & 63;
    const int g    = lane >> 4, lm = lane & 15;
    const int n0   = blockIdx.x * 32;
    const int b    = blockIdx.y;
    const float* xb = x + (size_t)b * CH * NPOS;

    bf16x8 xf[2][8];
    #pragma unroll
    for (int nt = 0; nt < 2; ++nt)
        #pragma unroll
        for (int kt = 0; kt < 8; ++kt) {
            const float* p = xb + (32 * kt + 8 * g) * NPOS + n0 + 16 * nt + lm;
            float v[8];
            #pragma unroll
            for (int j = 0; j < 8; ++j) v[j] = p[j * NPOS];
            xf[nt][kt] = pack8(v);
        }

    #pragma unroll
    for (int s = 0; s < 5; ++s) {
        const int cot = wave * 5 + s;
        const float* Wsrc; const float* bsrc; int cbase; int kind;
        if (cot < 2)      { Wsrc = Wq; bsrc = bq; cbase = cot * 16;      kind = 0; }
        else if (cot < 4) { Wsrc = Wk; bsrc = bk; cbase = cot * 16 - 32; kind = 1; }
        else              { Wsrc = Wv; bsrc = bv; cbase = cot * 16 - 64; kind = 2; }

        bf16x8 wf[8];
        const float* wrow = Wsrc + (size_t)(cbase + lm) * CH;
        #pragma unroll
        for (int kt = 0; kt < 8; ++kt) {
            float4 wa = *(const float4*)(wrow + 32 * kt + 8 * g);
            float4 wc = *(const float4*)(wrow + 32 * kt + 8 * g + 4);
            float wv[8] = {wa.x, wa.y, wa.z, wa.w, wc.x, wc.y, wc.z, wc.w};
            wf[kt] = pack8(wv);
        }
        const float4 b4 = *(const float4*)(bsrc + cbase + 4 * g);
        f32x4 a0 = {b4.x, b4.y, b4.z, b4.w};
        f32x4 a1 = a0;
        #pragma unroll
        for (int kt = 0; kt < 8; ++kt) {
            a0 = __builtin_amdgcn_mfma_f32_16x16x32_bf16(wf[kt], xf[0][kt], a0, 0, 0, 0);
            a1 = __builtin_amdgcn_mfma_f32_16x16x32_bf16(wf[kt], xf[1][kt], a1, 0, 0, 0);
        }

        if (kind <= 1) {
            __hip_bfloat16* dst = (kind == 0 ? qb : kb);
            #pragma unroll
            for (int nt = 0; nt < 2; ++nt) {
                f32x4 a = nt ? a1 : a0;
                int n = n0 + 16 * nt + lm;
                uint2 w;
                w.x = pack_bf2(a[0], a[1]);
                w.y = pack_bf2(a[2], a[3]);
                *(uint2*)(dst + ((size_t)b * NPOS + n) * DQK + cbase + 4 * g) = w;
            }
        } else {
            #pragma unroll
            for (int nt = 0; nt < 2; ++nt) {
                f32x4 a = nt ? a1 : a0;
                int n = n0 + 16 * nt + lm;
                int n64 = n >> 6, half = (n >> 5) & 1, nin = n & 31;
                #pragma unroll
                for (int r = 0; r < 4; ++r) {
                    int c = cbase + 4 * g + r;
                    size_t off = (((size_t)b * 16 + (c >> 4)) * 64 + n64) * 1024
                               + (size_t)half * 512 + (c & 15) * 32 + nin;
                    *reinterpret_cast<unsigned short*>(vb + off) = f2bf1(a[r]);
                }
            }
        }
    }
}

// ---------------- Kernel 2: cooperative MFMA flash, M=32 blocks (2 blocks/CU) ----------------
// grid 512: b = bid&3 (one batch per XCD), mblk = bid>>2 -> 32 m-rows/block.
// block 512 = 8 waves. Per 64-key tile t:
//   QK: wave (kt=w&3, mt=w>>2) computes 1 of 8 S^T subtiles -> exp -> P LDS.
//   PV: wave owns channels [32w,32w+32) x all 32 m.
// Double-buffered P (2x4KB), ONE barrier per tile. V/K register-double-buffered.
__global__ __launch_bounds__(512, 4) void flash_pam_kernel(
    const __hip_bfloat16* __restrict__ qb, const __hip_bfloat16* __restrict__ kb,
    const __hip_bfloat16* __restrict__ vb, const float* __restrict__ x,
    const float* __restrict__ gamma, float* __restrict__ out)
{
    __shared__ alignas(16) unsigned char Pl[2][4096];
    __shared__ float lred[4][2][16];   // [kt][mt][lm]

    const int tid  = threadIdx.x;
    const int wave = tid >> 6;
    const int lane = tid & 63;
    const int g    = lane >> 4;
    const int lm   = lane & 15;
    const int bid  = blockIdx.x;
    const int b    = bid & 3;
    const int m0   = (bid >> 2) * 32;
    const int kt   = wave & 3;
    const int mt_q = wave >> 2;
    const unsigned swz = (unsigned)(lm & 7) << 4;

    // Q B-fragment for this wave's S^T subtile
    const bf16x8 qfA = *reinterpret_cast<const bf16x8*>(
        qb + ((size_t)b * NPOS + m0 + 16 * mt_q + lm) * DQK + 8 * g);

    const __hip_bfloat16* kbb = kb + (size_t)b * NPOS * DQK;
    const int koff0 = (16 * kt + lm) * DQK + 8 * g;           // + t*2048
    const __hip_bfloat16* vbb = vb + (size_t)b * 16 * 64 * 1024;
    int vfb[4];                                                // + t*1024
    #pragma unroll
    for (int cti = 0; cti < 2; ++cti)
        #pragma unroll
        for (int kc = 0; kc < 2; ++kc)
            vfb[2 * cti + kc] = (2 * wave + cti) * 65536 + kc * 512 + lm * 32 + 8 * g;

    // P^T write offset: row m = 16*mt_q + lm (128 B/row), col byte k*2, XOR-swizzled
    const unsigned wbA = (unsigned)(16 * mt_q + lm) * 128
                       + (((unsigned)(32 * kt + 8 * g)) ^ swz);

    unsigned char* P0 = &Pl[0][0];
    unsigned char* P1 = &Pl[1][0];

    f32x4 acc[2][2];
    #pragma unroll
    for (int i = 0; i < 2; ++i)
        #pragma unroll
        for (int j = 0; j < 2; ++j) acc[i][j] = (f32x4){0.f, 0.f, 0.f, 0.f};
    float lsA = 0.f;

#define LOADK(dst, tk_) \
    dst = *reinterpret_cast<const bf16x8*>(kbb + koff0 + (tk_) * 2048);

#define LOADV(dst, tv_) { \
    _Pragma("unroll") for (int f = 0; f < 4; ++f) \
        dst[f] = *reinterpret_cast<const bf16x8*>(vbb + vfb[f] + (tv_) * 1024); }

#define QKW(KU, PW) { \
    f32x4 z = {0.f, 0.f, 0.f, 0.f}; \
    f32x4 sA = __builtin_amdgcn_mfma_f32_16x16x32_bf16(KU, qfA, z, 0, 0, 0); \
    float p0 = __expf(sA[0] - SHIFT), p1 = __expf(sA[1] - SHIFT); \
    float p2 = __expf(sA[2] - SHIFT), p3 = __expf(sA[3] - SHIFT); \
    lsA += (p0 + p1) + (p2 + p3); \
    uint2 w; w.x = pack_bf2(p0, p1); w.y = pack_bf2(p2, p3); \
    *reinterpret_cast<uint2*>((PW) + wbA) = w; }

#define PV(PR, VR) { \
    _Pragma("unroll") for (int kc = 0; kc < 2; ++kc) { \
        bf16x8 pf0 = *reinterpret_cast<const bf16x8*>( \
            (PR) + (unsigned)lm * 128 + (((unsigned)(kc * 64 + 16 * g)) ^ swz)); \
        bf16x8 pf1 = *reinterpret_cast<const bf16x8*>( \
            (PR) + (unsigned)(16 + lm) * 128 + (((unsigned)(kc * 64 + 16 * g)) ^ swz)); \
        _Pragma("unroll") for (int cti = 0; cti < 2; ++cti) { \
            acc[cti][0] = __builtin_amdgcn_mfma_f32_16x16x32_bf16( \
                VR[2 * cti + kc], pf0, acc[cti][0], 0, 0, 0); \
            acc[cti][1] = __builtin_amdgcn_mfma_f32_16x16x32_bf16( \
                VR[2 * cti + kc], pf1, acc[cti][1], 0, 0, 0); } } }

// BODY(t): prefetch V(t+1),K(t+2); QK(t+1)+exp -> PW; PV(t) from PR+VR; barrier.
#define BODY(t_, PR, PW, VR, VL, KU, KL) { \
    { int tv = (t_) + 1; if (tv > 63) tv = 63; LOADV(VL, tv); } \
    { int tk2 = (t_) + 2; if (tk2 > 63) tk2 = 63; LOADK(KL, tk2); } \
    QKW(KU, PW); \
    PV(PR, VR); \
    __syncthreads(); }

    // prologue
    bf16x8 kA, kB, vA[4], vB[4];
    LOADK(kA, 0);
    LOADV(vA, 0);
    LOADK(kB, 1);
    QKW(kA, P0);
    __syncthreads();

    for (int it = 0; it < 31; ++it) {
        BODY(2 * it,     P0, P1, vA, vB, kB, kA);
        BODY(2 * it + 1, P1, P0, vB, vA, kA, kB);
    }
    BODY(62, P0, P1, vA, vB, kB, kA);
    PV(P1, vB);   // t = 63

    // merge per-subtile l partials: reduce over g in-wave, over kt via LDS
    lsA += __shfl_xor(lsA, 16); lsA += __shfl_xor(lsA, 32);
    if (lane < 16) lred[kt][mt_q][lm] = lsA;
    __syncthreads();

    float linv[2];
    #pragma unroll
    for (int mt = 0; mt < 2; ++mt)
        linv[mt] = 1.f / (lred[0][mt][lm] + lred[1][mt][lm]
                        + lred[2][mt][lm] + lred[3][mt][lm]);

    const float gmv = gamma[0];
    #pragma unroll
    for (int cti = 0; cti < 2; ++cti)
        #pragma unroll
        for (int mt = 0; mt < 2; ++mt)
            #pragma unroll
            for (int r = 0; r < 4; ++r) {
                int c = 32 * wave + 16 * cti + 4 * g + r;
                size_t idx = ((size_t)b * CH + c) * NPOS + m0 + 16 * mt + lm;
                out[idx] = gmv * (acc[cti][mt][r] * linv[mt]) + x[idx];
            }
#undef BODY
#undef PV
#undef QKW
#undef LOADV
#undef LOADK
}

extern "C" void kernel_launch(void* const* d_in, const int* in_sizes, int n_in,
                              void* d_out, int out_size, void* d_ws, size_t ws_size,
                              hipStream_t stream) {
    const float* x  = (const float*)d_in[0];
    const float* Wq = (const float*)d_in[1];
    const float* bq = (const float*)d_in[2];
    const float* Wk = (const float*)d_in[3];
    const float* bk = (const float*)d_in[4];
    const float* Wv = (const float*)d_in[5];
    const float* bv = (const float*)d_in[6];
    const float* gm = (const float*)d_in[7];
    float* out = (float*)d_out;

    __hip_bfloat16* qbuf = (__hip_bfloat16*)d_ws;
    __hip_bfloat16* kbuf = qbuf + (size_t)BATCH * NPOS * DQK;
    __hip_bfloat16* vbuf = kbuf + (size_t)BATCH * NPOS * DQK;

    qkv_proj_mfma<<<dim3(NPOS / 32, BATCH), 256, 0, stream>>>(
        x, Wq, bq, Wk, bk, Wv, bv, qbuf, kbuf, vbuf);
    flash_pam_kernel<<<dim3(NPOS / 32 * BATCH), 512, 0, stream>>>(
        qbuf, kbuf, vbuf, x, gm, out);
}

// Round 8
// 75.098 us; speedup vs baseline: 1.4168x; 1.4168x over previous
//
#include <hip/hip_runtime.h>
#include <hip/hip_bf16.h>
#include <math.h>

#define BATCH 4
#define CH    256
#define NPOS  4096
#define DQK   32
#define SHIFT 20.0f

typedef __attribute__((ext_vector_type(8))) short bf16x8;
typedef __attribute__((ext_vector_type(4))) float f32x4;

static __device__ __forceinline__ unsigned int pack_bf2(float a, float b) {
    __hip_bfloat162 h = __float22bfloat162_rn(make_float2(a, b));
    return *reinterpret_cast<unsigned int*>(&h);
}
static __device__ __forceinline__ unsigned short f2bf1(float f) {
    unsigned int u = __float_as_uint(f);
    u += 0x7fff + ((u >> 16) & 1);
    return (unsigned short)(u >> 16);
}
static __device__ __forceinline__ bf16x8 pack8(const float* v) {
    bf16x8 r;
    #pragma unroll
    for (int j = 0; j < 8; ++j) r[j] = (short)f2bf1(v[j]);
    return r;
}

// Barrier WITHOUT the vmcnt(0) drain: LDS ops must be complete (cross-wave
// visibility), but register-destined global prefetches stay in flight.
static __device__ __forceinline__ void lds_barrier() {
    asm volatile("s_waitcnt lgkmcnt(0)" ::: "memory");
    __builtin_amdgcn_s_barrier();
    asm volatile("" ::: "memory");
}

// ---------------- Kernel 1: MFMA projection GEMM (unchanged from R6) ----------------
__global__ __launch_bounds__(256) void qkv_proj_mfma(
    const float* __restrict__ x,
    const float* __restrict__ Wq, const float* __restrict__ bq,
    const float* __restrict__ Wk, const float* __restrict__ bk,
    const float* __restrict__ Wv, const float* __restrict__ bv,
    __hip_bfloat16* __restrict__ qb, __hip_bfloat16* __restrict__ kb,
    __hip_bfloat16* __restrict__ vb)
{
    const int tid  = threadIdx.x;
    const int wave = tid >> 6, lane = tid & 63;
    const int g    = lane >> 4, lm = lane & 15;
    const int n0   = blockIdx.x * 32;
    const int b    = blockIdx.y;
    const float* xb = x + (size_t)b * CH * NPOS;

    bf16x8 xf[2][8];
    #pragma unroll
    for (int nt = 0; nt < 2; ++nt)
        #pragma unroll
        for (int kt = 0; kt < 8; ++kt) {
            const float* p = xb + (32 * kt + 8 * g) * NPOS + n0 + 16 * nt + lm;
            float v[8];
            #pragma unroll
            for (int j = 0; j < 8; ++j) v[j] = p[j * NPOS];
            xf[nt][kt] = pack8(v);
        }

    #pragma unroll
    for (int s = 0; s < 5; ++s) {
        const int cot = wave * 5 + s;
        const float* Wsrc; const float* bsrc; int cbase; int kind;
        if (cot < 2)      { Wsrc = Wq; bsrc = bq; cbase = cot * 16;      kind = 0; }
        else if (cot < 4) { Wsrc = Wk; bsrc = bk; cbase = cot * 16 - 32; kind = 1; }
        else              { Wsrc = Wv; bsrc = bv; cbase = cot * 16 - 64; kind = 2; }

        bf16x8 wf[8];
        const float* wrow = Wsrc + (size_t)(cbase + lm) * CH;
        #pragma unroll
        for (int kt = 0; kt < 8; ++kt) {
            float4 wa = *(const float4*)(wrow + 32 * kt + 8 * g);
            float4 wc = *(const float4*)(wrow + 32 * kt + 8 * g + 4);
            float wv[8] = {wa.x, wa.y, wa.z, wa.w, wc.x, wc.y, wc.z, wc.w};
            wf[kt] = pack8(wv);
        }
        const float4 b4 = *(const float4*)(bsrc + cbase + 4 * g);
        f32x4 a0 = {b4.x, b4.y, b4.z, b4.w};
        f32x4 a1 = a0;
        #pragma unroll
        for (int kt = 0; kt < 8; ++kt) {
            a0 = __builtin_amdgcn_mfma_f32_16x16x32_bf16(wf[kt], xf[0][kt], a0, 0, 0, 0);
            a1 = __builtin_amdgcn_mfma_f32_16x16x32_bf16(wf[kt], xf[1][kt], a1, 0, 0, 0);
        }

        if (kind <= 1) {
            __hip_bfloat16* dst = (kind == 0 ? qb : kb);
            #pragma unroll
            for (int nt = 0; nt < 2; ++nt) {
                f32x4 a = nt ? a1 : a0;
                int n = n0 + 16 * nt + lm;
                uint2 w;
                w.x = pack_bf2(a[0], a[1]);
                w.y = pack_bf2(a[2], a[3]);
                *(uint2*)(dst + ((size_t)b * NPOS + n) * DQK + cbase + 4 * g) = w;
            }
        } else {
            #pragma unroll
            for (int nt = 0; nt < 2; ++nt) {
                f32x4 a = nt ? a1 : a0;
                int n = n0 + 16 * nt + lm;
                int n64 = n >> 6, half = (n >> 5) & 1, nin = n & 31;
                #pragma unroll
                for (int r = 0; r < 4; ++r) {
                    int c = cbase + 4 * g + r;
                    size_t off = (((size_t)b * 16 + (c >> 4)) * 64 + n64) * 1024
                               + (size_t)half * 512 + (c & 15) * 32 + nin;
                    *reinterpret_cast<unsigned short*>(vb + off) = f2bf1(a[r]);
                }
            }
        }
    }
}

// ---------------- Kernel 2: cooperative MFMA flash (R6 geometry) ----------------
// grid 256: b = bid&3 (one batch per XCD), mblk = bid>>2 -> 64 m-rows/block.
// block 512 = 8 waves. Per key-tile t: QK wave-split 2/16 subtiles -> exp -> P LDS;
// PV: wave owns 32 channels x all 64 m. Double-buffered P, ONE raw-barrier/tile
// (lgkmcnt-only drain => V/K register prefetch survives across iterations).
__global__ __launch_bounds__(512) void flash_pam_kernel(
    const __hip_bfloat16* __restrict__ qb, const __hip_bfloat16* __restrict__ kb,
    const __hip_bfloat16* __restrict__ vb, const float* __restrict__ x,
    const float* __restrict__ gamma, float* __restrict__ out)
{
    __shared__ alignas(16) unsigned char Pl[2][8192];
    __shared__ float lred[4][4][16];   // [kt][mt][lm]

    const int tid  = threadIdx.x;
    const int wave = tid >> 6;
    const int lane = tid & 63;
    const int g    = lane >> 4;
    const int lm   = lane & 15;
    const int bid  = blockIdx.x;
    const int b    = bid & 3;
    const int m0   = (bid >> 2) * 64;
    const int kt   = wave & 3;
    const int mtA  = (wave >> 2) * 2;
    const unsigned swz = (unsigned)(lm & 7) << 4;

    const bf16x8 qfA = *reinterpret_cast<const bf16x8*>(
        qb + ((size_t)b * NPOS + m0 + 16 * mtA + lm) * DQK + 8 * g);
    const bf16x8 qfB = *reinterpret_cast<const bf16x8*>(
        qb + ((size_t)b * NPOS + m0 + 16 * mtA + 16 + lm) * DQK + 8 * g);

    const __hip_bfloat16* kbb = kb + (size_t)b * NPOS * DQK;
    const int koff0 = (16 * kt + lm) * DQK + 8 * g;           // + t*2048
    const __hip_bfloat16* vbb = vb + (size_t)b * 16 * 64 * 1024;
    int vfb[4];                                                // + t*1024
    #pragma unroll
    for (int cti = 0; cti < 2; ++cti)
        #pragma unroll
        for (int kc = 0; kc < 2; ++kc)
            vfb[2 * cti + kc] = (2 * wave + cti) * 65536 + kc * 512 + lm * 32 + 8 * g;

    const unsigned wbA = (unsigned)(16 * mtA + lm) * 128
                       + (((unsigned)(32 * kt + 8 * g)) ^ swz);
    const unsigned wbB = wbA + 16 * 128;

    unsigned char* P0 = &Pl[0][0];
    unsigned char* P1 = &Pl[1][0];

    f32x4 acc[2][4];
    #pragma unroll
    for (int i = 0; i < 2; ++i)
        #pragma unroll
        for (int j = 0; j < 4; ++j) acc[i][j] = (f32x4){0.f, 0.f, 0.f, 0.f};
    float lsA = 0.f, lsB = 0.f;

#define LOADK(dst, tk_) \
    dst = *reinterpret_cast<const bf16x8*>(kbb + koff0 + (tk_) * 2048);

#define LOADV(dst, tv_) { \
    _Pragma("unroll") for (int f = 0; f < 4; ++f) \
        dst[f] = *reinterpret_cast<const bf16x8*>(vbb + vfb[f] + (tv_) * 1024); }

#define QKW(KU, PW) { \
    f32x4 z = {0.f, 0.f, 0.f, 0.f}; \
    f32x4 sA = __builtin_amdgcn_mfma_f32_16x16x32_bf16(KU, qfA, z, 0, 0, 0); \
    f32x4 sB = __builtin_amdgcn_mfma_f32_16x16x32_bf16(KU, qfB, z, 0, 0, 0); \
    { float p0 = __expf(sA[0] - SHIFT), p1 = __expf(sA[1] - SHIFT); \
      float p2 = __expf(sA[2] - SHIFT), p3 = __expf(sA[3] - SHIFT); \
      lsA += (p0 + p1) + (p2 + p3); \
      uint2 w; w.x = pack_bf2(p0, p1); w.y = pack_bf2(p2, p3); \
      *reinterpret_cast<uint2*>((PW) + wbA) = w; } \
    { float p0 = __expf(sB[0] - SHIFT), p1 = __expf(sB[1] - SHIFT); \
      float p2 = __expf(sB[2] - SHIFT), p3 = __expf(sB[3] - SHIFT); \
      lsB += (p0 + p1) + (p2 + p3); \
      uint2 w; w.x = pack_bf2(p0, p1); w.y = pack_bf2(p2, p3); \
      *reinterpret_cast<uint2*>((PW) + wbB) = w; } }

#define PV(PR, VR) { \
    _Pragma("unroll") for (int kc = 0; kc < 2; ++kc) { \
        bf16x8 pf[4]; \
        _Pragma("unroll") for (int mt = 0; mt < 4; ++mt) \
            pf[mt] = *reinterpret_cast<const bf16x8*>( \
                (PR) + (unsigned)(16 * mt + lm) * 128 \
                     + (((unsigned)(kc * 64 + 16 * g)) ^ swz)); \
        __builtin_amdgcn_s_setprio(1); \
        _Pragma("unroll") for (int cti = 0; cti < 2; ++cti) \
            _Pragma("unroll") for (int mt = 0; mt < 4; ++mt) \
                acc[cti][mt] = __builtin_amdgcn_mfma_f32_16x16x32_bf16( \
                    VR[2 * cti + kc], pf[mt], acc[cti][mt], 0, 0, 0); \
        __builtin_amdgcn_s_setprio(0); } }

// BODY(t): prefetch V(t+1),K(t+2); QK(t+1)+exp -> PW; PV(t) from PR+VR; raw barrier.
#define BODY(t_, PR, PW, VR, VL, KU, KL) { \
    { int tv = (t_) + 1; if (tv > 63) tv = 63; LOADV(VL, tv); } \
    { int tk2 = (t_) + 2; if (tk2 > 63) tk2 = 63; LOADK(KL, tk2); } \
    QKW(KU, PW); \
    PV(PR, VR); \
    lds_barrier(); }

    // prologue
    bf16x8 kA, kB, vA[4], vB[4];
    LOADK(kA, 0);
    LOADV(vA, 0);
    LOADK(kB, 1);
    QKW(kA, P0);
    lds_barrier();

    for (int it = 0; it < 31; ++it) {
        BODY(2 * it,     P0, P1, vA, vB, kB, kA);
        BODY(2 * it + 1, P1, P0, vB, vA, kA, kB);
    }
    BODY(62, P0, P1, vA, vB, kB, kA);
    PV(P1, vB);   // t = 63

    // merge per-subtile l partials: reduce over g in-wave, over kt via LDS
    lsA += __shfl_xor(lsA, 16); lsA += __shfl_xor(lsA, 32);
    lsB += __shfl_xor(lsB, 16); lsB += __shfl_xor(lsB, 32);
    if (lane < 16) {
        lred[kt][mtA][lm]     = lsA;
        lred[kt][mtA + 1][lm] = lsB;
    }
    __syncthreads();

    float linv[4];
    #pragma unroll
    for (int mt = 0; mt < 4; ++mt)
        linv[mt] = 1.f / (lred[0][mt][lm] + lred[1][mt][lm]
                        + lred[2][mt][lm] + lred[3][mt][lm]);

    const float gmv = gamma[0];
    #pragma unroll
    for (int cti = 0; cti < 2; ++cti)
        #pragma unroll
        for (int mt = 0; mt < 4; ++mt)
            #pragma unroll
            for (int r = 0; r < 4; ++r) {
                int c = 32 * wave + 16 * cti + 4 * g + r;
                size_t idx = ((size_t)b * CH + c) * NPOS + m0 + 16 * mt + lm;
                out[idx] = gmv * (acc[cti][mt][r] * linv[mt]) + x[idx];
            }
#undef BODY
#undef PV
#undef QKW
#undef LOADV
#undef LOADK
}

extern "C" void kernel_launch(void* const* d_in, const int* in_sizes, int n_in,
                              void* d_out, int out_size, void* d_ws, size_t ws_size,
                              hipStream_t stream) {
    const float* x  = (const float*)d_in[0];
    const float* Wq = (const float*)d_in[1];
    const float* bq = (const float*)d_in[2];
    const float* Wk = (const float*)d_in[3];
    const float* bk = (const float*)d_in[4];
    const float* Wv = (const float*)d_in[5];
    const float* bv = (const float*)d_in[6];
    const float* gm = (const float*)d_in[7];
    float* out = (float*)d_out;

    __hip_bfloat16* qbuf = (__hip_bfloat16*)d_ws;
    __hip_bfloat16* kbuf = qbuf + (size_t)BATCH * NPOS * DQK;
    __hip_bfloat16* vbuf = kbuf + (size_t)BATCH * NPOS * DQK;

    qkv_proj_mfma<<<dim3(NPOS / 32, BATCH), 256, 0, stream>>>(
        x, Wq, bq, Wk, bk, Wv, bv, qbuf, kbuf, vbuf);
    flash_pam_kernel<<<dim3(NPOS / 64 * BATCH), 512, 0, stream>>>(
        qbuf, kbuf, vbuf, x, gm, out);
}